// Round 25
// baseline (104.136 us; speedup 1.0000x reference)
//
#include <hip/hip_runtime.h>
#include <hip/hip_fp16.h>

#define RH 128
#define RW 128
#define CS 21    // src channels
#define IH 512
#define IW 512
#define NPIX (RH * RW)
#define P 5          // dy split factor: 25/5 = 5 rows/wave, balanced
#define SPITCH 160   // padded srcP row pitch: 12 zero | 128 | 20 zero
#define SCH8 (RH * SPITCH)  // per-group plane stride in half8 units
#define IPITCH 152   // padded im row pitch: 12 reflect | 128 | 12 reflect
#define STW 88       // staged src window width per block (64 px + 24 halo)

// ---------------- K1: grid-fused {horizontal src downsample, 4 rows/thread} + {im downsample} + {counter zero} ----------------
#define NB_H (((IH / 4) * RW * CS + 255) / 256)   // 4 rows per thread
__global__ void fused_ds_kernel(const float* __restrict__ src, const float* __restrict__ im,
                                __half* __restrict__ tmpH, float2* __restrict__ imh,
                                unsigned* __restrict__ counters) {
    if (blockIdx.x == 0) counters[threadIdx.x] = 0;   // 256 group counters, zeroed每 call before K2
    if (blockIdx.x < NB_H) {
        int idx = blockIdx.x * 256 + threadIdx.x;
        if (idx >= (IH / 4) * RW * CS) return;
        int c = idx % CS;
        int t = idx / CS;
        int x = t % RW;
        int y4 = t / RW;                    // 0..127
        int y0 = y4 * 4;

        float sx = 4.f * x + 1.5f;
        float wx[8]; int jx[8]; float wxs = 0.f;
#pragma unroll
        for (int k = 0; k < 8; ++k) {
            int j = 4 * x - 2 + k;
            float w = 1.f - fabsf(sx - (float)j) * 0.25f;
            if (j < 0 || j >= IW) { w = 0.f; j = 0; }
            jx[k] = j; wx[k] = w; wxs += w;
        }
        float inv = 1.f / wxs;
#pragma unroll
        for (int r = 0; r < 4; ++r) {
            const float* row = src + (size_t)(y0 + r) * IW * CS + c;
            float s = 0.f;
#pragma unroll
            for (int b = 0; b < 8; ++b) s += wx[b] * row[jx[b] * CS];
            tmpH[((size_t)(y0 + r) * RW + x) * CS + c] = __float2half(s * inv);
        }
    } else {
        int idx = (blockIdx.x - NB_H) * 256 + threadIdx.x;
        if (idx >= RH * IPITCH) return;
        int xp = idx % IPITCH;
        int y = idx / IPITCH;
        int gx = xp - 12;
        gx = gx < 0 ? -gx : (gx > RW - 1 ? 2 * (RW - 1) - gx : gx);

        float wy[8], wx[8];
        int jy[8], jx[8];
        float sy = 4.f * y + 1.5f, sx = 4.f * gx + 1.5f;
        float wys = 0.f, wxs = 0.f;
#pragma unroll
        for (int k = 0; k < 8; ++k) {
            int j = 4 * y - 2 + k;
            float w = 1.f - fabsf(sy - (float)j) * 0.25f;
            if (j < 0 || j >= IH) { w = 0.f; j = 0; }
            jy[k] = j; wy[k] = w; wys += w;
            int j2 = 4 * gx - 2 + k;
            float w2 = 1.f - fabsf(sx - (float)j2) * 0.25f;
            if (j2 < 0 || j2 >= IW) { w2 = 0.f; j2 = 0; }
            jx[k] = j2; wx[k] = w2; wxs += w2;
        }
        float inv = 1.f / (wys * wxs);
        float s0 = 0.f, s1 = 0.f, s2 = 0.f;
#pragma unroll
        for (int a = 0; a < 8; ++a) {
            const float* row = im + (size_t)(jy[a] * IW) * 3;
            float r0 = 0.f, r1 = 0.f, r2 = 0.f;
#pragma unroll
            for (int b = 0; b < 8; ++b) {
                const float* pp = row + jx[b] * 3;
                r0 += wx[b] * pp[0];
                r1 += wx[b] * pp[1];
                r2 += wx[b] * pp[2];
            }
            s0 += wy[a] * r0; s1 += wy[a] * r1; s2 += wy[a] * r2;
        }
        float2 o;
        *reinterpret_cast<__half2*>(&o.x) = __floats2half2_rn(s0 * inv, s1 * inv);
        *reinterpret_cast<__half2*>(&o.y) = __floats2half2_rn(s2 * inv, 0.f);
        imh[idx] = o;
    }
}

// ---------------- K1a-V: vertical pass tmpH(fp16, [512][128][21]) -> packed half8 planar srcP[3][128][160] ----------------
__global__ void ds_src_v_kernel(const __half* __restrict__ tmpH, __half* __restrict__ srcP) {
    int idx = blockIdx.x * blockDim.x + threadIdx.x;
    if (idx >= RH * SPITCH * 24) return;
    int c = idx % 24;
    int t = idx / 24;
    int xp = t % SPITCH;
    int y = t / SPITCH;                 // output row 0..127
    int g = c >> 3;
    size_t oidx = ((size_t)(g * RH + y) * SPITCH + xp) * 8 + (c & 7);
    int x = xp - 12;
    if (c >= CS || x < 0 || x >= RW) { srcP[oidx] = __float2half(0.f); return; }

    float sy = 4.f * y + 1.5f;
    float wy[8]; int jy[8]; float wys = 0.f;
#pragma unroll
    for (int k = 0; k < 8; ++k) {
        int j = 4 * y - 2 + k;
        float w = 1.f - fabsf(sy - (float)j) * 0.25f;
        if (j < 0 || j >= IH) { w = 0.f; j = 0; }
        jy[k] = j; wy[k] = w; wys += w;
    }
    float s = 0.f;
#pragma unroll
    for (int a = 0; a < 8; ++a)
        s += wy[a] * __half2float(tmpH[((size_t)jy[a] * RW + x) * CS + c]);
    srcP[oidx] = __float2half(s / wys);
}

// ---------------- K2: joint bilateral; LDS-staged src; two-phase taps; last-arrival in-kernel reduce ----------------
__global__ __launch_bounds__(256) void bilateral_kernel(
        const float4* __restrict__ srcP8,  // [3][128][160] half8 elements, zero-padded
        const float2* __restrict__ imh,    // [128][152] half4 elements, reflect-padded
        __half* __restrict__ part,         // [P][21][NPIX] fp16
        float* __restrict__ outr24,        // [NPIX][24] interleaved padded
        unsigned* __restrict__ counters) { // [256] zeroed by fused_ds each call
    __shared__ float4 sst[5][3][STW];      // 21,120 B (reused as red[3][6][64] = 18,432 B)
    __shared__ int lastFlag;

    int tid = threadIdx.x;
    int w = tid >> 6;                      // dx quarter 0..3
    int lane = tid & 63;
    int bid = blockIdx.x;
    int p = bid >> 8;                      // 0..4
    int pxw = bid & 255;
    int h = pxw & 1;
    int y = pxw >> 1;
    int xbase = h << 6;
    int x = xbase + lane;

    // ---- stage the block's entire src working set: rows y+p+5r-12, window [xbase, xbase+88) ----
    for (int t = tid; t < 5 * 3 * STW; t += 256) {
        int r = t / (3 * STW);
        int rem = t - r * (3 * STW);
        int g = rem / STW;
        int i = rem - g * STW;
        int ry = y + p + 5 * r - 12;
        float4 v = {0.f, 0.f, 0.f, 0.f};
        if (ry >= 0 && ry < RH)
            v = srcP8[(size_t)(g * RH + ry) * SPITCH + xbase + i];
        sst[r][g][i] = v;
    }
    __syncthreads();

    float2 craw = imh[y * IPITCH + x + 12];
    __half2 ch01 = *reinterpret_cast<__half2*>(&craw.x);
    __half2 ch23 = *reinterpret_cast<__half2*>(&craw.y);
    float2 f01 = __half22float2(ch01);
    float c0 = f01.x, c1 = f01.y, c2 = __half2float(__low2half(ch23));

    float4 a0 = {0,0,0,0}, a1 = {0,0,0,0}, a2 = {0,0,0,0},
           a3 = {0,0,0,0}, a4 = {0,0,0,0}, a5 = {0,0,0,0};

    for (int r = 0; r < 5; ++r) {
        int dy = p + 5 * r;                // 0..24, exactly 25 covered across p
        int ry = y + dy - 12;
        int ryc = min(max(ry, 0), RH - 1); // clamp for im only; OOB src rows staged as zero
        float fdy = (float)(dy - 12);
        float gy = fdy * fdy;
        const float2* irow = imh + ryc * IPITCH + x;

        // ---- phase A: all 7 im loads + exp chains up front ----
        float cwv[7];
#pragma unroll
        for (int i = 0; i < 7; ++i) {
            int dx = w + 4 * i;
            int dxc = min(dx, 24);
            float2 raw = irow[dxc];
            __half2 h01 = *reinterpret_cast<__half2*>(&raw.x);
            __half2 h23 = *reinterpret_cast<__half2*>(&raw.y);
            float2 rg = __half22float2(h01);
            float d0 = rg.x - c0;
            float d1 = rg.y - c1;
            float d2 = __half2float(__low2half(h23)) - c2;
            float fdx = (float)(dx - 12);
            float e = -(d0 * d0 + d1 * d1 + d2 * d2) * (1.f / 18.f)
                      - (gy + fdx * fdx) * (1.f / 128.f);
            cwv[i] = (dx < 25) ? __expf(e) : 0.f;
        }

        // ---- phase B: pure LDS-read + packed-fma sweep ----
        __half2 hacc[12];
#pragma unroll
        for (int k = 0; k < 12; ++k) hacc[k] = __floats2half2_rn(0.f, 0.f);

#pragma unroll
        for (int i = 0; i < 7; ++i) {
            int dxc = min(w + 4 * i, 24);
            __half2 cw2 = __float2half2_rn(cwv[i]);
            float4 s0 = sst[r][0][lane + dxc];
            float4 s1 = sst[r][1][lane + dxc];
            float4 s2 = sst[r][2][lane + dxc];
            const __half2* h0 = reinterpret_cast<const __half2*>(&s0);
            const __half2* h1 = reinterpret_cast<const __half2*>(&s1);
            const __half2* h2 = reinterpret_cast<const __half2*>(&s2);
#pragma unroll
            for (int k = 0; k < 4; ++k) {
                hacc[k]     = __hfma2(cw2, h0[k], hacc[k]);
                hacc[4 + k] = __hfma2(cw2, h1[k], hacc[4 + k]);
                hacc[8 + k] = __hfma2(cw2, h2[k], hacc[8 + k]);
            }
        }
        // unpack per-dy into fp32 accumulators
        float2 u;
        u = __half22float2(hacc[0]);  a0.x += u.x; a0.y += u.y;
        u = __half22float2(hacc[1]);  a0.z += u.x; a0.w += u.y;
        u = __half22float2(hacc[2]);  a1.x += u.x; a1.y += u.y;
        u = __half22float2(hacc[3]);  a1.z += u.x; a1.w += u.y;
        u = __half22float2(hacc[4]);  a2.x += u.x; a2.y += u.y;
        u = __half22float2(hacc[5]);  a2.z += u.x; a2.w += u.y;
        u = __half22float2(hacc[6]);  a3.x += u.x; a3.y += u.y;
        u = __half22float2(hacc[7]);  a3.z += u.x; a3.w += u.y;
        u = __half22float2(hacc[8]);  a4.x += u.x; a4.y += u.y;
        u = __half22float2(hacc[9]);  a4.z += u.x; a4.w += u.y;
        u = __half22float2(hacc[10]); a5.x += u.x; a5.y += u.y;
        u = __half22float2(hacc[11]); a5.z += u.x; a5.w += u.y;
    }

    // ---- reuse sst storage as the cross-wave reduce buffer ----
    __syncthreads();                       // all sst reads complete before overwrite
    float4* redp = &sst[0][0][0];
    if (w > 0) {
        int base = (w - 1) * 6 * 64 + lane;
        redp[base + 0 * 64] = a0; redp[base + 1 * 64] = a1; redp[base + 2 * 64] = a2;
        redp[base + 3 * 64] = a3; redp[base + 4 * 64] = a4; redp[base + 5 * 64] = a5;
    }
    __syncthreads();
    if (w == 0) {
        float4 b[6] = {a0, a1, a2, a3, a4, a5};
#pragma unroll
        for (int k = 0; k < 6; ++k) {
#pragma unroll
            for (int r = 0; r < 3; ++r) {
                float4 v = redp[(r * 6 + k) * 64 + lane];
                b[k].x += v.x; b[k].y += v.y; b[k].z += v.z; b[k].w += v.w;
            }
        }
        int pix = (y << 7) + x;
        __half* po = part + ((size_t)(p * CS) << 14) + pix;
#pragma unroll
        for (int c = 0; c < CS; ++c) {
            float v = (&b[c >> 2].x)[c & 3];
            po[(size_t)c << 14] = __float2half(v);
        }
    }

    // ---- last-arrival cross-block reduction (deterministic: fixed p-order sum) ----
    __syncthreads();                       // partial stores issued by wave 0
    if (tid == 0) {
        __threadfence();                   // publish this block's partials device-wide
        unsigned old = atomicAdd(&counters[pxw], 1u);
        lastFlag = (old == 4u);
    }
    __syncthreads();
    if (lastFlag) {
        __threadfence();                   // acquire other blocks' partials
        int q0 = ((y << 7) + xbase) >> 2;  // 16 quads of this 64-pixel group
        for (int t2 = tid; t2 < CS * 16; t2 += 256) {
            int c = t2 >> 4;
            int q = t2 & 15;
            int pix0 = (q0 + q) << 2;
            float4 s = {0, 0, 0, 0};
#pragma unroll
            for (int pp = 0; pp < P; ++pp) {
                const __half* pb = part + ((size_t)(pp * CS + c) << 14) + pix0;
                __half2 v01 = *reinterpret_cast<const __half2*>(pb);
                __half2 v23 = *reinterpret_cast<const __half2*>(pb + 2);
                float2 g01 = __half22float2(v01);
                float2 g23 = __half22float2(v23);
                s.x += g01.x; s.y += g01.y; s.z += g23.x; s.w += g23.y;
            }
            outr24[(size_t)(pix0 + 0) * 24 + c] = s.x;
            outr24[(size_t)(pix0 + 1) * 24 + c] = s.y;
            outr24[(size_t)(pix0 + 2) * 24 + c] = s.z;
            outr24[(size_t)(pix0 + 3) * 24 + c] = s.w;
        }
    }
}

// ---------------- K3: bilinear upsample 128 -> 512; thread = (pixel, 4-ch group), float4 loads ----------------
__global__ void upsample_kernel(const float4* __restrict__ inr24, float* __restrict__ out) {
    int idx = blockIdx.x * blockDim.x + threadIdx.x;
    if (idx >= IH * IW * 6) return;
    int g = idx % 6;                 // g fastest: wave covers ~10 contiguous 96B pixel records
    int t = idx / 6;
    int X = t % IW, Y = t / IW;
    float fy = 0.25f * (float)Y - 0.375f;
    float fx = 0.25f * (float)X - 0.375f;
    int y0 = (int)floorf(fy); float ty = fy - (float)y0;
    int x0 = (int)floorf(fx); float tx = fx - (float)x0;
    int y1 = y0 + 1, x1 = x0 + 1;
    y0 = min(max(y0, 0), RH - 1); y1 = min(max(y1, 0), RH - 1);
    x0 = min(max(x0, 0), RW - 1); x1 = min(max(x1, 0), RW - 1);
    float4 v00 = inr24[((y0 << 7) + x0) * 6 + g], v01 = inr24[((y0 << 7) + x1) * 6 + g];
    float4 v10 = inr24[((y1 << 7) + x0) * 6 + g], v11 = inr24[((y1 << 7) + x1) * 6 + g];
    float4 v0, v1, r;
    v0.x = v00.x + tx * (v01.x - v00.x); v1.x = v10.x + tx * (v11.x - v10.x);
    v0.y = v00.y + tx * (v01.y - v00.y); v1.y = v10.y + tx * (v11.y - v10.y);
    v0.z = v00.z + tx * (v01.z - v00.z); v1.z = v10.z + tx * (v11.z - v10.z);
    v0.w = v00.w + tx * (v01.w - v00.w); v1.w = v10.w + tx * (v11.w - v10.w);
    r.x = v0.x + ty * (v1.x - v0.x);
    r.y = v0.y + ty * (v1.y - v0.y);
    r.z = v0.z + ty * (v1.z - v0.z);
    r.w = v0.w + ty * (v1.w - v0.w);
    float* o = out + (size_t)(Y * IW + X) * CS + 4 * g;
    if (g < 5) { o[0] = r.x; o[1] = r.y; o[2] = r.z; o[3] = r.w; }
    else       { o[0] = r.x; }   // c = 20 only
}

extern "C" void kernel_launch(void* const* d_in, const int* in_sizes, int n_in,
                              void* d_out, int out_size, void* d_ws, size_t ws_size,
                              hipStream_t stream) {
    const float* src = (const float*)d_in[0];   // (1,512,512,21) f32
    const float* im  = (const float*)d_in[1];   // (1,512,512,3)  f32
    float* out = (float*)d_out;                 // (1,512,512,21) f32 = 22,020,096 B
    char* ws = (char*)d_ws;

    // scratch in d_out (fully overwritten by K3 at the end, stream-ordered):
    __half* tmpH = (__half*)d_out;                      // [512][128][21] fp16 = 2,752,512 B
    __half* part = (__half*)d_out;                      // [5][21][16384] fp16 = 3,440,640 B (after tmpH consumed)
    __half* srcP = (__half*)((char*)d_out + 21037056);  // [3][128][160] half8 = 983,040 B (ends exactly 22,020,096)
    // small scratch in ws (1,729,536 B):
    float2* imh  = (float2*)ws;                         // [128][152] half4 = 155,648 B
    float* out_r24 = (float*)(ws + 155648);             // [16384][24] f32  = 1,572,864 B
    unsigned* counters = (unsigned*)(ws + 1728512);     // [256] u32       =     1,024 B

    int nb_im = (RH * IPITCH + 255) / 256;
    fused_ds_kernel<<<NB_H + nb_im, 256, 0, stream>>>(src, im, tmpH, imh, counters);

    int tv = RH * SPITCH * 24;
    ds_src_v_kernel<<<(tv + 255) / 256, 256, 0, stream>>>(tmpH, srcP);

    // 5 dy-groups x 256 half-rows = 1280 blocks x 4 waves; last-arrival block reduces its group
    bilateral_kernel<<<P * 256, 256, 0, stream>>>((const float4*)srcP, imh, part, out_r24, counters);

    int t3 = IH * IW * 6;
    upsample_kernel<<<(t3 + 255) / 256, 256, 0, stream>>>((const float4*)out_r24, out);
}

// Round 26
// 58.016 us; speedup vs baseline: 1.7949x; 1.7949x over previous
//
#include <hip/hip_runtime.h>
#include <hip/hip_fp16.h>

#define RH 128
#define RW 128
#define CS 21    // src channels
#define IH 512
#define IW 512
#define NPIX (RH * RW)
#define P 5          // dy split factor: 25/5 = 5 rows/wave, balanced
#define SPITCH 160   // padded srcP row pitch: 12 zero | 128 | 20 zero
#define SCH8 (RH * SPITCH)  // per-group plane stride in half8 units
#define IPITCH 152   // padded im row pitch: 12 reflect | 128 | 12 reflect
#define STW 88       // staged src window width per block (64 px + 24 halo)

// ---------------- K1: grid-fused {horizontal src downsample, 4 rows/thread -> fp16 tmpH[512][128][21]} + {im downsample (half4)} ----------------
#define NB_H (((IH / 4) * RW * CS + 255) / 256)   // 4 rows per thread
__global__ void fused_ds_kernel(const float* __restrict__ src, const float* __restrict__ im,
                                __half* __restrict__ tmpH, float2* __restrict__ imh) {
    if (blockIdx.x < NB_H) {
        int idx = blockIdx.x * 256 + threadIdx.x;
        if (idx >= (IH / 4) * RW * CS) return;
        int c = idx % CS;
        int t = idx / CS;
        int x = t % RW;
        int y4 = t / RW;                    // 0..127
        int y0 = y4 * 4;

        float sx = 4.f * x + 1.5f;
        float wx[8]; int jx[8]; float wxs = 0.f;
#pragma unroll
        for (int k = 0; k < 8; ++k) {
            int j = 4 * x - 2 + k;
            float w = 1.f - fabsf(sx - (float)j) * 0.25f;
            if (j < 0 || j >= IW) { w = 0.f; j = 0; }
            jx[k] = j; wx[k] = w; wxs += w;
        }
        float inv = 1.f / wxs;
#pragma unroll
        for (int r = 0; r < 4; ++r) {
            const float* row = src + (size_t)(y0 + r) * IW * CS + c;
            float s = 0.f;
#pragma unroll
            for (int b = 0; b < 8; ++b) s += wx[b] * row[jx[b] * CS];
            tmpH[((size_t)(y0 + r) * RW + x) * CS + c] = __float2half(s * inv);
        }
    } else {
        int idx = (blockIdx.x - NB_H) * 256 + threadIdx.x;
        if (idx >= RH * IPITCH) return;
        int xp = idx % IPITCH;
        int y = idx / IPITCH;
        int gx = xp - 12;
        gx = gx < 0 ? -gx : (gx > RW - 1 ? 2 * (RW - 1) - gx : gx);

        float wy[8], wx[8];
        int jy[8], jx[8];
        float sy = 4.f * y + 1.5f, sx = 4.f * gx + 1.5f;
        float wys = 0.f, wxs = 0.f;
#pragma unroll
        for (int k = 0; k < 8; ++k) {
            int j = 4 * y - 2 + k;
            float w = 1.f - fabsf(sy - (float)j) * 0.25f;
            if (j < 0 || j >= IH) { w = 0.f; j = 0; }
            jy[k] = j; wy[k] = w; wys += w;
            int j2 = 4 * gx - 2 + k;
            float w2 = 1.f - fabsf(sx - (float)j2) * 0.25f;
            if (j2 < 0 || j2 >= IW) { w2 = 0.f; j2 = 0; }
            jx[k] = j2; wx[k] = w2; wxs += w2;
        }
        float inv = 1.f / (wys * wxs);
        float s0 = 0.f, s1 = 0.f, s2 = 0.f;
#pragma unroll
        for (int a = 0; a < 8; ++a) {
            const float* row = im + (size_t)(jy[a] * IW) * 3;
            float r0 = 0.f, r1 = 0.f, r2 = 0.f;
#pragma unroll
            for (int b = 0; b < 8; ++b) {
                const float* pp = row + jx[b] * 3;
                r0 += wx[b] * pp[0];
                r1 += wx[b] * pp[1];
                r2 += wx[b] * pp[2];
            }
            s0 += wy[a] * r0; s1 += wy[a] * r1; s2 += wy[a] * r2;
        }
        float2 o;
        *reinterpret_cast<__half2*>(&o.x) = __floats2half2_rn(s0 * inv, s1 * inv);
        *reinterpret_cast<__half2*>(&o.y) = __floats2half2_rn(s2 * inv, 0.f);
        imh[idx] = o;
    }
}

// ---------------- K1a-V: vertical pass, 4 xp per thread (y-weights computed once) ----------------
__global__ void ds_src_v_kernel(const __half* __restrict__ tmpH, __half* __restrict__ srcP) {
    int idx = blockIdx.x * blockDim.x + threadIdx.x;
    if (idx >= RH * (SPITCH / 4) * 24) return;
    int c = idx % 24;
    int t = idx / 24;
    int xq = t % (SPITCH / 4);
    int y = t / (SPITCH / 4);           // output row 0..127
    int xp0 = xq * 4;
    int g = c >> 3;

    float sy = 4.f * y + 1.5f;
    float wy[8]; int jy[8]; float wys = 0.f;
#pragma unroll
    for (int k = 0; k < 8; ++k) {
        int j = 4 * y - 2 + k;
        float w = 1.f - fabsf(sy - (float)j) * 0.25f;
        if (j < 0 || j >= IH) { w = 0.f; j = 0; }
        jy[k] = j; wy[k] = w; wys += w;
    }
    float inv = 1.f / wys;

#pragma unroll
    for (int i = 0; i < 4; ++i) {
        int xp = xp0 + i;
        size_t oidx = ((size_t)(g * RH + y) * SPITCH + xp) * 8 + (c & 7);
        int x = xp - 12;
        if (c >= CS || x < 0 || x >= RW) { srcP[oidx] = __float2half(0.f); continue; }
        float s = 0.f;
#pragma unroll
        for (int a = 0; a < 8; ++a)
            s += wy[a] * __half2float(tmpH[((size_t)jy[a] * RW + x) * CS + c]);
        srcP[oidx] = __float2half(s * inv);
    }
}

// ---------------- K2: joint bilateral; LDS-staged src; per-row two-phase (cw precompute, then hfma sweep) ----------------
__global__ __launch_bounds__(256) void bilateral_kernel(
        const float4* __restrict__ srcP8,  // [3][128][160] half8 elements, zero-padded
        const float2* __restrict__ imh,    // [128][152] half4 elements, reflect-padded
        __half* __restrict__ part) {       // [P][21][NPIX] fp16
    __shared__ float4 sst[5][3][STW];      // 21,120 B (reused as red[3][6][64] = 18,432 B)

    int tid = threadIdx.x;
    int w = tid >> 6;                      // dx quarter 0..3
    int lane = tid & 63;
    int bid = blockIdx.x;
    int p = bid >> 8;                      // 0..4
    int pxw = bid & 255;
    int h = pxw & 1;
    int y = pxw >> 1;
    int xbase = h << 6;
    int x = xbase + lane;

    // ---- stage the block's entire src working set: rows y+p+5r-12, window [xbase, xbase+88) ----
    for (int t = tid; t < 5 * 3 * STW; t += 256) {
        int r = t / (3 * STW);
        int rem = t - r * (3 * STW);
        int g = rem / STW;
        int i = rem - g * STW;
        int ry = y + p + 5 * r - 12;
        float4 v = {0.f, 0.f, 0.f, 0.f};
        if (ry >= 0 && ry < RH)
            v = srcP8[(size_t)(g * RH + ry) * SPITCH + xbase + i];
        sst[r][g][i] = v;
    }
    __syncthreads();

    float2 craw = imh[y * IPITCH + x + 12];
    __half2 ch01 = *reinterpret_cast<__half2*>(&craw.x);
    __half2 ch23 = *reinterpret_cast<__half2*>(&craw.y);
    float2 f01 = __half22float2(ch01);
    float c0 = f01.x, c1 = f01.y, c2 = __half2float(__low2half(ch23));

    float4 a0 = {0,0,0,0}, a1 = {0,0,0,0}, a2 = {0,0,0,0},
           a3 = {0,0,0,0}, a4 = {0,0,0,0}, a5 = {0,0,0,0};

    for (int r = 0; r < 5; ++r) {
        int dy = p + 5 * r;                // 0..24, exactly 25 covered across p
        int ry = y + dy - 12;
        int ryc = min(max(ry, 0), RH - 1); // clamp for im only; OOB src rows staged as zero
        float fdy = (float)(dy - 12);
        float gy = fdy * fdy;
        const float2* irow = imh + ryc * IPITCH + x;

        // ---- phase A: all 7 im loads + exp chains up front (7-deep latency hiding) ----
        float cwv[7];
#pragma unroll
        for (int i = 0; i < 7; ++i) {
            int dx = w + 4 * i;
            int dxc = min(dx, 24);         // clamped address; masked below
            float2 raw = irow[dxc];
            __half2 h01 = *reinterpret_cast<__half2*>(&raw.x);
            __half2 h23 = *reinterpret_cast<__half2*>(&raw.y);
            float2 rg = __half22float2(h01);
            float d0 = rg.x - c0;
            float d1 = rg.y - c1;
            float d2 = __half2float(__low2half(h23)) - c2;
            float fdx = (float)(dx - 12);
            float e = -(d0 * d0 + d1 * d1 + d2 * d2) * (1.f / 18.f)
                      - (gy + fdx * fdx) * (1.f / 128.f);
            cwv[i] = (dx < 25) ? __expf(e) : 0.f;
        }

        // ---- phase B: pure LDS-read + packed-fma sweep ----
        __half2 hacc[12];
#pragma unroll
        for (int k = 0; k < 12; ++k) hacc[k] = __floats2half2_rn(0.f, 0.f);

#pragma unroll
        for (int i = 0; i < 7; ++i) {
            int dxc = min(w + 4 * i, 24);
            __half2 cw2 = __float2half2_rn(cwv[i]);
            float4 s0 = sst[r][0][lane + dxc];
            float4 s1 = sst[r][1][lane + dxc];
            float4 s2 = sst[r][2][lane + dxc];
            const __half2* h0 = reinterpret_cast<const __half2*>(&s0);
            const __half2* h1 = reinterpret_cast<const __half2*>(&s1);
            const __half2* h2 = reinterpret_cast<const __half2*>(&s2);
#pragma unroll
            for (int k = 0; k < 4; ++k) {
                hacc[k]     = __hfma2(cw2, h0[k], hacc[k]);
                hacc[4 + k] = __hfma2(cw2, h1[k], hacc[4 + k]);
                hacc[8 + k] = __hfma2(cw2, h2[k], hacc[8 + k]);
            }
        }
        // unpack per-dy into fp32 accumulators
        float2 u;
        u = __half22float2(hacc[0]);  a0.x += u.x; a0.y += u.y;
        u = __half22float2(hacc[1]);  a0.z += u.x; a0.w += u.y;
        u = __half22float2(hacc[2]);  a1.x += u.x; a1.y += u.y;
        u = __half22float2(hacc[3]);  a1.z += u.x; a1.w += u.y;
        u = __half22float2(hacc[4]);  a2.x += u.x; a2.y += u.y;
        u = __half22float2(hacc[5]);  a2.z += u.x; a2.w += u.y;
        u = __half22float2(hacc[6]);  a3.x += u.x; a3.y += u.y;
        u = __half22float2(hacc[7]);  a3.z += u.x; a3.w += u.y;
        u = __half22float2(hacc[8]);  a4.x += u.x; a4.y += u.y;
        u = __half22float2(hacc[9]);  a4.z += u.x; a4.w += u.y;
        u = __half22float2(hacc[10]); a5.x += u.x; a5.y += u.y;
        u = __half22float2(hacc[11]); a5.z += u.x; a5.w += u.y;
    }

    // ---- reuse sst storage as the cross-wave reduce buffer ----
    __syncthreads();                       // all sst reads complete before overwrite
    float4* redp = &sst[0][0][0];
    if (w > 0) {
        int base = (w - 1) * 6 * 64 + lane;
        redp[base + 0 * 64] = a0; redp[base + 1 * 64] = a1; redp[base + 2 * 64] = a2;
        redp[base + 3 * 64] = a3; redp[base + 4 * 64] = a4; redp[base + 5 * 64] = a5;
    }
    __syncthreads();
    if (w == 0) {
        float4 b[6] = {a0, a1, a2, a3, a4, a5};
#pragma unroll
        for (int k = 0; k < 6; ++k) {
#pragma unroll
            for (int r = 0; r < 3; ++r) {
                float4 v = redp[(r * 6 + k) * 64 + lane];
                b[k].x += v.x; b[k].y += v.y; b[k].z += v.z; b[k].w += v.w;
            }
        }
        int pix = (y << 7) + x;
        __half* po = part + ((size_t)(p * CS) << 14) + pix;
#pragma unroll
        for (int c = 0; c < CS; ++c) {
            float v = (&b[c >> 2].x)[c & 3];
            po[(size_t)c << 14] = __float2half(v);
        }
    }
}

// ---------------- K2b: reduce fp16 partials (4 pixels) -> interleaved padded out_r24[pix][24] ----------------
__global__ void reduce_kernel(const __half* __restrict__ part, float* __restrict__ outr24) {
    int t = blockIdx.x * blockDim.x + threadIdx.x;
    if (t >= CS * (NPIX / 4)) return;
    int c = t >> 12;                 // 0..20
    int i4 = t & 4095;
    int pix0 = i4 << 2;
    float4 s = {0, 0, 0, 0};
#pragma unroll
    for (int p = 0; p < P; ++p) {
        const __half* pp = part + ((size_t)(p * CS + c) << 14) + pix0;
        __half2 v01 = *reinterpret_cast<const __half2*>(pp);
        __half2 v23 = *reinterpret_cast<const __half2*>(pp + 2);
        float2 f01 = __half22float2(v01);
        float2 f23 = __half22float2(v23);
        s.x += f01.x; s.y += f01.y; s.z += f23.x; s.w += f23.y;
    }
    outr24[(size_t)(pix0 + 0) * 24 + c] = s.x;
    outr24[(size_t)(pix0 + 1) * 24 + c] = s.y;
    outr24[(size_t)(pix0 + 2) * 24 + c] = s.z;
    outr24[(size_t)(pix0 + 3) * 24 + c] = s.w;
}

// ---------------- K3: bilinear upsample 128 -> 512; thread = (pixel, 4-ch group), float4 loads ----------------
__global__ void upsample_kernel(const float4* __restrict__ inr24, float* __restrict__ out) {
    int idx = blockIdx.x * blockDim.x + threadIdx.x;
    if (idx >= IH * IW * 6) return;
    int g = idx % 6;                 // g fastest: wave covers ~10 contiguous 96B pixel records
    int t = idx / 6;
    int X = t % IW, Y = t / IW;
    float fy = 0.25f * (float)Y - 0.375f;
    float fx = 0.25f * (float)X - 0.375f;
    int y0 = (int)floorf(fy); float ty = fy - (float)y0;
    int x0 = (int)floorf(fx); float tx = fx - (float)x0;
    int y1 = y0 + 1, x1 = x0 + 1;
    y0 = min(max(y0, 0), RH - 1); y1 = min(max(y1, 0), RH - 1);
    x0 = min(max(x0, 0), RW - 1); x1 = min(max(x1, 0), RW - 1);
    float4 v00 = inr24[((y0 << 7) + x0) * 6 + g], v01 = inr24[((y0 << 7) + x1) * 6 + g];
    float4 v10 = inr24[((y1 << 7) + x0) * 6 + g], v11 = inr24[((y1 << 7) + x1) * 6 + g];
    float4 v0, v1, r;
    v0.x = v00.x + tx * (v01.x - v00.x); v1.x = v10.x + tx * (v11.x - v10.x);
    v0.y = v00.y + tx * (v01.y - v00.y); v1.y = v10.y + tx * (v11.y - v10.y);
    v0.z = v00.z + tx * (v01.z - v00.z); v1.z = v10.z + tx * (v11.z - v10.z);
    v0.w = v00.w + tx * (v01.w - v00.w); v1.w = v10.w + tx * (v11.w - v10.w);
    r.x = v0.x + ty * (v1.x - v0.x);
    r.y = v0.y + ty * (v1.y - v0.y);
    r.z = v0.z + ty * (v1.z - v0.z);
    r.w = v0.w + ty * (v1.w - v0.w);
    float* o = out + (size_t)(Y * IW + X) * CS + 4 * g;
    if (g < 5) { o[0] = r.x; o[1] = r.y; o[2] = r.z; o[3] = r.w; }
    else       { o[0] = r.x; }   // c = 20 only
}

extern "C" void kernel_launch(void* const* d_in, const int* in_sizes, int n_in,
                              void* d_out, int out_size, void* d_ws, size_t ws_size,
                              hipStream_t stream) {
    const float* src = (const float*)d_in[0];   // (1,512,512,21) f32
    const float* im  = (const float*)d_in[1];   // (1,512,512,3)  f32
    float* out = (float*)d_out;                 // (1,512,512,21) f32 = 22,020,096 B
    char* ws = (char*)d_ws;

    // scratch in d_out (fully overwritten by K3 at the end, stream-ordered):
    __half* tmpH = (__half*)d_out;                      // [512][128][21] fp16 = 2,752,512 B
    __half* part = (__half*)d_out;                      // [5][21][16384] fp16 = 3,440,640 B (after tmpH consumed)
    __half* srcP = (__half*)((char*)d_out + 21037056);  // [3][128][160] half8 = 983,040 B (ends exactly 22,020,096)
    // small scratch in ws (1,728,512 B):
    float2* imh  = (float2*)ws;                         // [128][152] half4 = 155,648 B
    float* out_r24 = (float*)(ws + 155648);             // [16384][24] f32  = 1,572,864 B

    int nb_im = (RH * IPITCH + 255) / 256;
    fused_ds_kernel<<<NB_H + nb_im, 256, 0, stream>>>(src, im, tmpH, imh);

    int tv = RH * (SPITCH / 4) * 24;
    ds_src_v_kernel<<<(tv + 255) / 256, 256, 0, stream>>>(tmpH, srcP);

    // 5 dy-groups x 256 half-rows = 1280 blocks x 4 waves; 21.1 KB LDS -> 5 blocks/CU resident
    bilateral_kernel<<<P * 256, 256, 0, stream>>>((const float4*)srcP, imh, part);

    int tr = CS * (NPIX / 4);
    reduce_kernel<<<(tr + 255) / 256, 256, 0, stream>>>(part, out_r24);

    int t3 = IH * IW * 6;
    upsample_kernel<<<(t3 + 255) / 256, 256, 0, stream>>>((const float4*)out_r24, out);
}

// Round 27
// 52.249 us; speedup vs baseline: 1.9931x; 1.1104x over previous
//
#include <hip/hip_runtime.h>
#include <hip/hip_fp16.h>

#define RH 128
#define RW 128
#define CS 21    // src channels
#define IH 512
#define IW 512
#define NPIX (RH * RW)
#define P 5          // dy split factor: 25/5 = 5 rows/wave, balanced
#define SPITCH 160   // padded srcP row pitch: 12 zero | 128 | 20 zero
#define SCH8 (RH * SPITCH)  // per-group plane stride in half8 units
#define IPITCH 152   // padded im row pitch: 12 reflect | 128 | 12 reflect
#define STW 88       // staged src window width per block (64 px + 24 halo)
#define UT 16        // merged reduce+upsample output tile

// ---------------- K1: grid-fused {horizontal src downsample, 4 rows/thread -> fp16 tmpH[512][128][21]} + {im downsample (half4)} ----------------
#define NB_H (((IH / 4) * RW * CS + 255) / 256)   // 4 rows per thread
__global__ void fused_ds_kernel(const float* __restrict__ src, const float* __restrict__ im,
                                __half* __restrict__ tmpH, float2* __restrict__ imh) {
    if (blockIdx.x < NB_H) {
        int idx = blockIdx.x * 256 + threadIdx.x;
        if (idx >= (IH / 4) * RW * CS) return;
        int c = idx % CS;
        int t = idx / CS;
        int x = t % RW;
        int y4 = t / RW;                    // 0..127
        int y0 = y4 * 4;

        float sx = 4.f * x + 1.5f;
        float wx[8]; int jx[8]; float wxs = 0.f;
#pragma unroll
        for (int k = 0; k < 8; ++k) {
            int j = 4 * x - 2 + k;
            float w = 1.f - fabsf(sx - (float)j) * 0.25f;
            if (j < 0 || j >= IW) { w = 0.f; j = 0; }
            jx[k] = j; wx[k] = w; wxs += w;
        }
        float inv = 1.f / wxs;
#pragma unroll
        for (int r = 0; r < 4; ++r) {
            const float* row = src + (size_t)(y0 + r) * IW * CS + c;
            float s = 0.f;
#pragma unroll
            for (int b = 0; b < 8; ++b) s += wx[b] * row[jx[b] * CS];
            tmpH[((size_t)(y0 + r) * RW + x) * CS + c] = __float2half(s * inv);
        }
    } else {
        int idx = (blockIdx.x - NB_H) * 256 + threadIdx.x;
        if (idx >= RH * IPITCH) return;
        int xp = idx % IPITCH;
        int y = idx / IPITCH;
        int gx = xp - 12;
        gx = gx < 0 ? -gx : (gx > RW - 1 ? 2 * (RW - 1) - gx : gx);

        float wy[8], wx[8];
        int jy[8], jx[8];
        float sy = 4.f * y + 1.5f, sx = 4.f * gx + 1.5f;
        float wys = 0.f, wxs = 0.f;
#pragma unroll
        for (int k = 0; k < 8; ++k) {
            int j = 4 * y - 2 + k;
            float w = 1.f - fabsf(sy - (float)j) * 0.25f;
            if (j < 0 || j >= IH) { w = 0.f; j = 0; }
            jy[k] = j; wy[k] = w; wys += w;
            int j2 = 4 * gx - 2 + k;
            float w2 = 1.f - fabsf(sx - (float)j2) * 0.25f;
            if (j2 < 0 || j2 >= IW) { w2 = 0.f; j2 = 0; }
            jx[k] = j2; wx[k] = w2; wxs += w2;
        }
        float inv = 1.f / (wys * wxs);
        float s0 = 0.f, s1 = 0.f, s2 = 0.f;
#pragma unroll
        for (int a = 0; a < 8; ++a) {
            const float* row = im + (size_t)(jy[a] * IW) * 3;
            float r0 = 0.f, r1 = 0.f, r2 = 0.f;
#pragma unroll
            for (int b = 0; b < 8; ++b) {
                const float* pp = row + jx[b] * 3;
                r0 += wx[b] * pp[0];
                r1 += wx[b] * pp[1];
                r2 += wx[b] * pp[2];
            }
            s0 += wy[a] * r0; s1 += wy[a] * r1; s2 += wy[a] * r2;
        }
        float2 o;
        *reinterpret_cast<__half2*>(&o.x) = __floats2half2_rn(s0 * inv, s1 * inv);
        *reinterpret_cast<__half2*>(&o.y) = __floats2half2_rn(s2 * inv, 0.f);
        imh[idx] = o;
    }
}

// ---------------- K1a-V: vertical pass tmpH(fp16, [512][128][21]) -> packed half8 planar srcP[3][128][160] ----------------
__global__ void ds_src_v_kernel(const __half* __restrict__ tmpH, __half* __restrict__ srcP) {
    int idx = blockIdx.x * blockDim.x + threadIdx.x;
    if (idx >= RH * SPITCH * 24) return;
    int c = idx % 24;
    int t = idx / 24;
    int xp = t % SPITCH;
    int y = t / SPITCH;                 // output row 0..127
    int g = c >> 3;
    size_t oidx = ((size_t)(g * RH + y) * SPITCH + xp) * 8 + (c & 7);
    int x = xp - 12;
    if (c >= CS || x < 0 || x >= RW) { srcP[oidx] = __float2half(0.f); return; }

    float sy = 4.f * y + 1.5f;
    float wy[8]; int jy[8]; float wys = 0.f;
#pragma unroll
    for (int k = 0; k < 8; ++k) {
        int j = 4 * y - 2 + k;
        float w = 1.f - fabsf(sy - (float)j) * 0.25f;
        if (j < 0 || j >= IH) { w = 0.f; j = 0; }
        jy[k] = j; wy[k] = w; wys += w;
    }
    float s = 0.f;
#pragma unroll
    for (int a = 0; a < 8; ++a)
        s += wy[a] * __half2float(tmpH[((size_t)jy[a] * RW + x) * CS + c]);
    srcP[oidx] = __float2half(s / wys);
}

// ---------------- K2: joint bilateral; LDS-staged src; per-row two-phase (cw precompute, then hfma sweep) ----------------
__global__ __launch_bounds__(256) void bilateral_kernel(
        const float4* __restrict__ srcP8,  // [3][128][160] half8 elements, zero-padded
        const float2* __restrict__ imh,    // [128][152] half4 elements, reflect-padded
        __half* __restrict__ part) {       // [P][21][NPIX] fp16
    __shared__ float4 sst[5][3][STW];      // 21,120 B (reused as red[3][6][64] = 18,432 B)

    int tid = threadIdx.x;
    int w = tid >> 6;                      // dx quarter 0..3
    int lane = tid & 63;
    int bid = blockIdx.x;
    int p = bid >> 8;                      // 0..4
    int pxw = bid & 255;
    int h = pxw & 1;
    int y = pxw >> 1;
    int xbase = h << 6;
    int x = xbase + lane;

    for (int t = tid; t < 5 * 3 * STW; t += 256) {
        int r = t / (3 * STW);
        int rem = t - r * (3 * STW);
        int g = rem / STW;
        int i = rem - g * STW;
        int ry = y + p + 5 * r - 12;
        float4 v = {0.f, 0.f, 0.f, 0.f};
        if (ry >= 0 && ry < RH)
            v = srcP8[(size_t)(g * RH + ry) * SPITCH + xbase + i];
        sst[r][g][i] = v;
    }
    __syncthreads();

    float2 craw = imh[y * IPITCH + x + 12];
    __half2 ch01 = *reinterpret_cast<__half2*>(&craw.x);
    __half2 ch23 = *reinterpret_cast<__half2*>(&craw.y);
    float2 f01 = __half22float2(ch01);
    float c0 = f01.x, c1 = f01.y, c2 = __half2float(__low2half(ch23));

    float4 a0 = {0,0,0,0}, a1 = {0,0,0,0}, a2 = {0,0,0,0},
           a3 = {0,0,0,0}, a4 = {0,0,0,0}, a5 = {0,0,0,0};

    for (int r = 0; r < 5; ++r) {
        int dy = p + 5 * r;                // 0..24, exactly 25 covered across p
        int ry = y + dy - 12;
        int ryc = min(max(ry, 0), RH - 1); // clamp for im only; OOB src rows staged as zero
        float fdy = (float)(dy - 12);
        float gy = fdy * fdy;
        const float2* irow = imh + ryc * IPITCH + x;

        float cwv[7];
#pragma unroll
        for (int i = 0; i < 7; ++i) {
            int dx = w + 4 * i;
            int dxc = min(dx, 24);
            float2 raw = irow[dxc];
            __half2 h01 = *reinterpret_cast<__half2*>(&raw.x);
            __half2 h23 = *reinterpret_cast<__half2*>(&raw.y);
            float2 rg = __half22float2(h01);
            float d0 = rg.x - c0;
            float d1 = rg.y - c1;
            float d2 = __half2float(__low2half(h23)) - c2;
            float fdx = (float)(dx - 12);
            float e = -(d0 * d0 + d1 * d1 + d2 * d2) * (1.f / 18.f)
                      - (gy + fdx * fdx) * (1.f / 128.f);
            cwv[i] = (dx < 25) ? __expf(e) : 0.f;
        }

        __half2 hacc[12];
#pragma unroll
        for (int k = 0; k < 12; ++k) hacc[k] = __floats2half2_rn(0.f, 0.f);

#pragma unroll
        for (int i = 0; i < 7; ++i) {
            int dxc = min(w + 4 * i, 24);
            __half2 cw2 = __float2half2_rn(cwv[i]);
            float4 s0 = sst[r][0][lane + dxc];
            float4 s1 = sst[r][1][lane + dxc];
            float4 s2 = sst[r][2][lane + dxc];
            const __half2* h0 = reinterpret_cast<const __half2*>(&s0);
            const __half2* h1 = reinterpret_cast<const __half2*>(&s1);
            const __half2* h2 = reinterpret_cast<const __half2*>(&s2);
#pragma unroll
            for (int k = 0; k < 4; ++k) {
                hacc[k]     = __hfma2(cw2, h0[k], hacc[k]);
                hacc[4 + k] = __hfma2(cw2, h1[k], hacc[4 + k]);
                hacc[8 + k] = __hfma2(cw2, h2[k], hacc[8 + k]);
            }
        }
        float2 u;
        u = __half22float2(hacc[0]);  a0.x += u.x; a0.y += u.y;
        u = __half22float2(hacc[1]);  a0.z += u.x; a0.w += u.y;
        u = __half22float2(hacc[2]);  a1.x += u.x; a1.y += u.y;
        u = __half22float2(hacc[3]);  a1.z += u.x; a1.w += u.y;
        u = __half22float2(hacc[4]);  a2.x += u.x; a2.y += u.y;
        u = __half22float2(hacc[5]);  a2.z += u.x; a2.w += u.y;
        u = __half22float2(hacc[6]);  a3.x += u.x; a3.y += u.y;
        u = __half22float2(hacc[7]);  a3.z += u.x; a3.w += u.y;
        u = __half22float2(hacc[8]);  a4.x += u.x; a4.y += u.y;
        u = __half22float2(hacc[9]);  a4.z += u.x; a4.w += u.y;
        u = __half22float2(hacc[10]); a5.x += u.x; a5.y += u.y;
        u = __half22float2(hacc[11]); a5.z += u.x; a5.w += u.y;
    }

    __syncthreads();
    float4* redp = &sst[0][0][0];
    if (w > 0) {
        int base = (w - 1) * 6 * 64 + lane;
        redp[base + 0 * 64] = a0; redp[base + 1 * 64] = a1; redp[base + 2 * 64] = a2;
        redp[base + 3 * 64] = a3; redp[base + 4 * 64] = a4; redp[base + 5 * 64] = a5;
    }
    __syncthreads();
    if (w == 0) {
        float4 b[6] = {a0, a1, a2, a3, a4, a5};
#pragma unroll
        for (int k = 0; k < 6; ++k) {
#pragma unroll
            for (int r = 0; r < 3; ++r) {
                float4 v = redp[(r * 6 + k) * 64 + lane];
                b[k].x += v.x; b[k].y += v.y; b[k].z += v.z; b[k].w += v.w;
            }
        }
        int pix = (y << 7) + x;
        __half* po = part + ((size_t)(p * CS) << 14) + pix;
#pragma unroll
        for (int c = 0; c < CS; ++c) {
            float v = (&b[c >> 2].x)[c & 3];
            po[(size_t)c << 14] = __float2half(v);
        }
    }
}

// ---------------- K3-merged: per-tile partial reduce into LDS + bilinear upsample (no out_r round trip) ----------------
__global__ __launch_bounds__(256) void reduce_up_kernel(const __half* __restrict__ part,
                                                        float* __restrict__ out) {
    __shared__ float red[6][6][24];        // 6x6 input window x 24 padded channels = 13,824 B
    int tid = threadIdx.x;
    int b = blockIdx.x;
    int X0 = (b & 31) << 4;
    int Y0 = (b >> 5) << 4;
    int ry0 = (Y0 >> 2) - 1;               // input window rows ry0..ry0+5 (clamped)
    int rx0 = (X0 >> 2) - 1;

    // phase 1: reduce 5 partial planes for the 6x6 x 21 window into LDS (deterministic p-order)
    for (int t = tid; t < 36 * CS; t += 256) {
        int c = t / 36;
        int rem = t - c * 36;
        int py = rem / 6, px = rem - (rem / 6) * 6;
        int gy = min(max(ry0 + py, 0), RH - 1);
        int gx = min(max(rx0 + px, 0), RW - 1);
        int pix = (gy << 7) + gx;
        float s = 0.f;
#pragma unroll
        for (int p = 0; p < P; ++p)
            s += __half2float(part[((size_t)(p * CS + c) << 14) + pix]);
        red[py][px][c] = s;
    }
    for (int t = tid; t < 36 * 3; t += 256) {   // zero channel pad 21..23
        int c = 21 + t / 36;
        int rem = t % 36;
        red[rem / 6][rem % 6][c] = 0.f;
    }
    __syncthreads();

    // phase 2: 16x16 outputs x 6 channel-groups, bilinear from LDS
    for (int t = tid; t < UT * UT * 6; t += 256) {
        int g = t % 6;
        int t2 = t / 6;
        int xloc = t2 % UT;
        int yloc = t2 / UT;
        int X = X0 + xloc, Y = Y0 + yloc;
        float fy = 0.25f * (float)Y - 0.375f;
        float fx = 0.25f * (float)X - 0.375f;
        int y0 = (int)floorf(fy); float ty = fy - (float)y0;
        int x0 = (int)floorf(fx); float tx = fx - (float)x0;
        int j0 = min(max(y0, 0), RH - 1) - ry0;
        int j1 = min(max(y0 + 1, 0), RH - 1) - ry0;
        int i0 = min(max(x0, 0), RW - 1) - rx0;
        int i1 = min(max(x0 + 1, 0), RW - 1) - rx0;
        const float* p00 = &red[j0][i0][4 * g];
        const float* p01 = &red[j0][i1][4 * g];
        const float* p10 = &red[j1][i0][4 * g];
        const float* p11 = &red[j1][i1][4 * g];
        float4 v00 = *reinterpret_cast<const float4*>(p00);
        float4 v01 = *reinterpret_cast<const float4*>(p01);
        float4 v10 = *reinterpret_cast<const float4*>(p10);
        float4 v11 = *reinterpret_cast<const float4*>(p11);
        float4 v0, v1, r;
        v0.x = v00.x + tx * (v01.x - v00.x); v1.x = v10.x + tx * (v11.x - v10.x);
        v0.y = v00.y + tx * (v01.y - v00.y); v1.y = v10.y + tx * (v11.y - v10.y);
        v0.z = v00.z + tx * (v01.z - v00.z); v1.z = v10.z + tx * (v11.z - v10.z);
        v0.w = v00.w + tx * (v01.w - v00.w); v1.w = v10.w + tx * (v11.w - v10.w);
        r.x = v0.x + ty * (v1.x - v0.x);
        r.y = v0.y + ty * (v1.y - v0.y);
        r.z = v0.z + ty * (v1.z - v0.z);
        r.w = v0.w + ty * (v1.w - v0.w);
        float* o = out + (size_t)(Y * IW + X) * CS + 4 * g;
        if (g < 5) { o[0] = r.x; o[1] = r.y; o[2] = r.z; o[3] = r.w; }
        else       { o[0] = r.x; }
    }
}

// ---------------- fallback K2b + K3 (used when ws is too small for part) ----------------
__global__ void reduce_kernel(const __half* __restrict__ part, float* __restrict__ outr24) {
    int t = blockIdx.x * blockDim.x + threadIdx.x;
    if (t >= CS * (NPIX / 4)) return;
    int c = t >> 12;
    int i4 = t & 4095;
    int pix0 = i4 << 2;
    float4 s = {0, 0, 0, 0};
#pragma unroll
    for (int p = 0; p < P; ++p) {
        const __half* pp = part + ((size_t)(p * CS + c) << 14) + pix0;
        __half2 v01 = *reinterpret_cast<const __half2*>(pp);
        __half2 v23 = *reinterpret_cast<const __half2*>(pp + 2);
        float2 f01 = __half22float2(v01);
        float2 f23 = __half22float2(v23);
        s.x += f01.x; s.y += f01.y; s.z += f23.x; s.w += f23.y;
    }
    outr24[(size_t)(pix0 + 0) * 24 + c] = s.x;
    outr24[(size_t)(pix0 + 1) * 24 + c] = s.y;
    outr24[(size_t)(pix0 + 2) * 24 + c] = s.z;
    outr24[(size_t)(pix0 + 3) * 24 + c] = s.w;
}

__global__ void upsample_kernel(const float4* __restrict__ inr24, float* __restrict__ out) {
    int idx = blockIdx.x * blockDim.x + threadIdx.x;
    if (idx >= IH * IW * 6) return;
    int g = idx % 6;
    int t = idx / 6;
    int X = t % IW, Y = t / IW;
    float fy = 0.25f * (float)Y - 0.375f;
    float fx = 0.25f * (float)X - 0.375f;
    int y0 = (int)floorf(fy); float ty = fy - (float)y0;
    int x0 = (int)floorf(fx); float tx = fx - (float)x0;
    int y1 = y0 + 1, x1 = x0 + 1;
    y0 = min(max(y0, 0), RH - 1); y1 = min(max(y1, 0), RH - 1);
    x0 = min(max(x0, 0), RW - 1); x1 = min(max(x1, 0), RW - 1);
    float4 v00 = inr24[((y0 << 7) + x0) * 6 + g], v01 = inr24[((y0 << 7) + x1) * 6 + g];
    float4 v10 = inr24[((y1 << 7) + x0) * 6 + g], v11 = inr24[((y1 << 7) + x1) * 6 + g];
    float4 v0, v1, r;
    v0.x = v00.x + tx * (v01.x - v00.x); v1.x = v10.x + tx * (v11.x - v10.x);
    v0.y = v00.y + tx * (v01.y - v00.y); v1.y = v10.y + tx * (v11.y - v10.y);
    v0.z = v00.z + tx * (v01.z - v00.z); v1.z = v10.z + tx * (v11.z - v10.z);
    v0.w = v00.w + tx * (v01.w - v00.w); v1.w = v10.w + tx * (v11.w - v10.w);
    r.x = v0.x + ty * (v1.x - v0.x);
    r.y = v0.y + ty * (v1.y - v0.y);
    r.z = v0.z + ty * (v1.z - v0.z);
    r.w = v0.w + ty * (v1.w - v0.w);
    float* o = out + (size_t)(Y * IW + X) * CS + 4 * g;
    if (g < 5) { o[0] = r.x; o[1] = r.y; o[2] = r.z; o[3] = r.w; }
    else       { o[0] = r.x; }
}

extern "C" void kernel_launch(void* const* d_in, const int* in_sizes, int n_in,
                              void* d_out, int out_size, void* d_ws, size_t ws_size,
                              hipStream_t stream) {
    const float* src = (const float*)d_in[0];   // (1,512,512,21) f32
    const float* im  = (const float*)d_in[1];   // (1,512,512,3)  f32
    float* out = (float*)d_out;                 // (1,512,512,21) f32 = 22,020,096 B
    char* ws = (char*)d_ws;

    const size_t PART_BYTES = (size_t)P * CS * NPIX * 2;   // 3,440,640
    bool merged = ws_size >= PART_BYTES;

    __half* tmpH = (__half*)d_out;                      // [512][128][21] fp16 = 2,752,512 B
    __half* srcP = (__half*)((char*)d_out + 21037056);  // [3][128][160] half8 = 983,040 B (tail)

    if (merged) {
        // part in ws; imh parked in d_out (consumed by K2 before the final full-d_out write)
        __half* part = (__half*)ws;                     // [5][21][16384] fp16 = 3,440,640 B
        float2* imh  = (float2*)((char*)d_out + 16777216);  // [128][152] half4 = 155,648 B (16MB..16.15MB, clear of tmpH/srcP)

        int nb_im = (RH * IPITCH + 255) / 256;
        fused_ds_kernel<<<NB_H + nb_im, 256, 0, stream>>>(src, im, tmpH, imh);

        int tv = RH * SPITCH * 24;
        ds_src_v_kernel<<<(tv + 255) / 256, 256, 0, stream>>>(tmpH, srcP);

        bilateral_kernel<<<P * 256, 256, 0, stream>>>((const float4*)srcP, imh, part);

        reduce_up_kernel<<<(IW / UT) * (IH / UT), 256, 0, stream>>>(part, out);
    } else {
        // R24 fallback: part in d_out, out_r24 in ws
        __half* part = (__half*)d_out;                  // reuses tmpH space after consumption
        float2* imh  = (float2*)ws;                     // 155,648 B
        float* out_r24 = (float*)(ws + 155648);         // 1,572,864 B

        int nb_im = (RH * IPITCH + 255) / 256;
        fused_ds_kernel<<<NB_H + nb_im, 256, 0, stream>>>(src, im, tmpH, imh);

        int tv = RH * SPITCH * 24;
        ds_src_v_kernel<<<(tv + 255) / 256, 256, 0, stream>>>(tmpH, srcP);

        bilateral_kernel<<<P * 256, 256, 0, stream>>>((const float4*)srcP, imh, part);

        int tr = CS * (NPIX / 4);
        reduce_kernel<<<(tr + 255) / 256, 256, 0, stream>>>(part, out_r24);

        int t3 = IH * IW * 6;
        upsample_kernel<<<(t3 + 255) / 256, 256, 0, stream>>>((const float4*)out_r24, out);
    }
}